// Round 21
// baseline (559.694 us; speedup 1.0000x reference)
//
#include <hip/hip_runtime.h>

typedef unsigned short u16;
typedef __attribute__((ext_vector_type(8))) short short8;
typedef __attribute__((ext_vector_type(4))) float f32x4;

#define FLAG_BIAS   1
#define FLAG_TANH   2
#define FLAG_MASK   4
#define FLAG_BF16   8
#define FLAG_NSTORE 16
#define FLAG_TSTORE 32
#define FLAG_SPLITN 64
#define FLAG_SCORE  128

__device__ __forceinline__ float fast_tanh(float x) {
  return 1.f - 2.f / (__expf(2.f * x) + 1.f);
}

__device__ __forceinline__ u16 f2bf(float f) {
  unsigned u = __float_as_uint(f);
  return (u16)((u + 0x7fffu + ((u >> 16) & 1u)) >> 16); // RNE
}

__device__ __forceinline__ unsigned cvtpk(float lo, float hi) {
  unsigned r;
  asm("v_cvt_pk_bf16_f32 %0, %1, %2" : "=v"(r) : "v"(lo), "v"(hi));
  return r;
}

__device__ __forceinline__ void gload_lds16(const void* g, void* l) {
  __builtin_amdgcn_global_load_lds(
      (const __attribute__((address_space(1))) unsigned int*)g,
      (__attribute__((address_space(3))) unsigned int*)l, 16, 0, 0);
}

// ---------------------------------------------------------------------------
// Generic GEMM: Out[r][c] = sum_k X[r][k] * Y[c][k]
//   TRX=0: 3-buffer prefetch-2 pipeline, raw s_barrier + counted vmcnt.
//   TRX=1: reg-transpose staged X, 2-buffer __syncthreads loop.
// BM=128, BN=128/256, BK=32, 4 waves, mfma_f32_16x16x32_bf16.
// 1-D grid, XCD-chunked swizzle. f32 4x32 LDS-bounce epilogue, cvt_pk on read.
// LDS sizing: TSTORE bounce (BN=128) needs 64*132*4 = 33792 B (R6/R7 bug).
// FLAG_SCORE (f32 NSTORE): partial dot over this block's BN-col slice ->
//   sout[half*shs + lsc*sls + bz*(gy*128) + row], half=(cb>>7)&1. Disjoint
//   per-block writes; consumers sum the halves. Deterministic.
// DUAL-M (msplit>0): rows >= msplit use the *2 parameter set and row index
//   rb-gofs / g-gofs. Block-uniform (msplit % 128 == 0). Used to merge:
//   (a) Whc+Whp weight GEMMs (NSTORE, CLW/PLW contiguous in d_out),
//   (b) C2Pt+P2Ct weight GEMMs (TSTORE, explicit X2/Tout2 strides).
// R17/R18 wins kept: all !TRX GEMMs at BN=128 -> 49 KB LDS -> 3 blocks/CU.
// ---------------------------------------------------------------------------
template <int BN, int TRX>
__global__ __launch_bounds__(256)
void gemm_nt(const u16* __restrict__ X, long long xbs, long long xls, int ldx,
             const u16* __restrict__ Y, long long ybs, long long yls, int ldy,
             void* __restrict__ Outv, long long obs, long long ols, int obase, int ldo,
             u16* __restrict__ Tout, long long tobs, long long tols, int tldo,
             int K, int gx, int gy, int flags,
             const float* __restrict__ bias,
             const int* __restrict__ rmask, int rms,
             const int* __restrict__ cmask, int cms,
             const float* __restrict__ sbase, float* __restrict__ sout,
             long long sls, int svoff, long long shs,
             const u16* __restrict__ X2, long long xbs2,
             const u16* __restrict__ Y2, const float* __restrict__ bias2,
             const float* __restrict__ sbase2, float* __restrict__ sout2,
             long long sls2, long long shs2,
             u16* __restrict__ Tout2, long long tobs2, int tldo2, int msplit) {
  constexpr int NACC = BN / 32;
  constexpr int YB = BN * 32 * 2;             // Y bytes per buffer
  constexpr int XB = TRX ? 8704 : 8192;       // X bytes per buffer (TRX: [128][34])
  constexpr int BUFB = XB + YB;
  constexpr int NBUF = TRX ? 2 : 3;           // pipeline depth
  constexpr int BW = BN + 4;                  // f32 bounce row stride
  constexpr int NSTB = 32 * BW * 4;           // NSTORE bounce bytes
  constexpr int TSTB = (BN == 128 && !TRX) ? 64 * 132 * 4 : 0;  // TSTORE bounce
  constexpr int EPIB = (NSTB > TSTB) ? NSTB : TSTB;
  constexpr int SMEMB = (NBUF * BUFB > EPIB) ? NBUF * BUFB : EPIB;
  __shared__ __align__(16) char smem[SMEMB];
  const int t = threadIdx.x;
  const int lane = t & 63, wid = t >> 6;
  const int wr = (wid >> 1) * 64, wc = (wid & 1) * (BN / 2);
  // XCD-chunked bijective swizzle (gridDim.x % 8 == 0 for all launches)
  const int lin = blockIdx.x;
  const int w = (lin & 7) * ((int)gridDim.x >> 3) + (lin >> 3);
  const int bx = w % gx;
  const int wy = w / gx;
  const int by = wy % gy;
  const int z = wy / gy;
  const int bz = z & 15, lz = z >> 4;
  const int rb = by * 128;
  const int cb = bx * BN;
  // DUAL-M block-uniform selection
  const bool dual = (msplit > 0) && (rb >= msplit);
  const u16* Xeff = dual ? X2 : X;
  const long long xbsE = dual ? xbs2 : xbs;
  const u16* Yeff = dual ? Y2 : Y;
  const float* biasE = dual ? bias2 : bias;
  const float* sbaseE = dual ? sbase2 : sbase;
  float* soutE = dual ? sout2 : sout;
  const long long slsE = dual ? sls2 : sls;
  const long long shsE = dual ? shs2 : shs;
  u16* ToutE = dual ? Tout2 : Tout;
  const long long tobsE = dual ? tobs2 : tobs;
  const int tldoE = dual ? tldo2 : tldo;
  const int gofs = dual ? msplit : 0;
  // TRX: rb indexes X *columns* (M); rows are K.
  const u16* Xb = Xeff + (size_t)bz * xbsE + (size_t)lz * xls +
                  (TRX ? (size_t)(rb - gofs) : (size_t)(rb - gofs) * ldx);
  const u16* Yb = Yeff + (size_t)bz * ybs + (size_t)lz * yls + (size_t)cb * ldy;
  const int srow = t >> 2, scol = (t & 3) * 8;
  const int r16 = lane & 15, kh = (lane >> 4) * 8;

  f32x4 acc[4][NACC];
#pragma unroll
  for (int m = 0; m < 4; m++)
#pragma unroll
    for (int n = 0; n < NACC; n++) acc[m][n] = (f32x4){0.f, 0.f, 0.f, 0.f};

  auto stageY = [&](int buf, int kk) {
    char* dst = smem + buf * BUFB + XB + t * 16;
#pragma unroll
    for (int j = 0; j < YB / 4096; j++)
      gload_lds16(Yb + (size_t)(j * 64 + srow) * ldy + kk + scol, dst + j * 4096);
  };
  auto stageX = [&](int buf, int kk) {
    char* dst = smem + buf * BUFB + t * 16;
#pragma unroll
    for (int j = 0; j < 2; j++)
      gload_lds16(Xb + (size_t)(j * 64 + srow) * ldx + kk + scol, dst + j * 4096);
  };
  auto stage = [&](int buf, int kk) { stageX(buf, kk); stageY(buf, kk); };
  // TRX register staging: load 2 K-rows x 8 M-cols, write transposed pairs
  uint4 xa, xb2;
  const int tc0 = (t >> 4) * 2, tp8 = (t & 15) * 8;
  auto xload = [&](int kk) {
    xa  = *(const uint4*)&Xb[(size_t)(kk + tc0) * ldx + tp8];
    xb2 = *(const uint4*)&Xb[(size_t)(kk + tc0 + 1) * ldx + tp8];
  };
  auto xwrite = [&](int buf) {
    u16* xt = (u16*)(smem + buf * BUFB);
    const unsigned* a = (const unsigned*)&xa;
    const unsigned* b = (const unsigned*)&xb2;
#pragma unroll
    for (int w2 = 0; w2 < 4; w2++) {
      const unsigned lo = (a[w2] & 0xffffu) | (b[w2] << 16);
      const unsigned hi = (a[w2] >> 16) | (b[w2] & 0xffff0000u);
      *(unsigned*)&xt[(size_t)(tp8 + 2 * w2) * 34 + tc0] = lo;
      *(unsigned*)&xt[(size_t)(tp8 + 2 * w2 + 1) * 34 + tc0] = hi;
    }
  };

  const int nt = K >> 5;
  if constexpr (!TRX) {
    // --- 3-buffer prefetch-2 pipeline, counted vmcnt, one s_barrier/iter ---
    stage(0, 0);
    if (nt > 1) stage(1, 32);
    int cur = 0;
    for (int tt = 0; tt < nt; ++tt) {
      if (tt + 1 < nt) {
        if constexpr (BN == 128) asm volatile("s_waitcnt vmcnt(4)" ::: "memory");
        else                     asm volatile("s_waitcnt vmcnt(6)" ::: "memory");
      } else {
        asm volatile("s_waitcnt vmcnt(0)" ::: "memory");
      }
      __builtin_amdgcn_sched_barrier(0);
      __builtin_amdgcn_s_barrier();   // all waves: tile tt resident in buf cur
      if (tt + 2 < nt) {
        int nxt = cur + 2; if (nxt >= 3) nxt -= 3;
        stage(nxt, (tt + 2) * 32);
      }
      const u16* lx = (const u16*)(smem + cur * BUFB);
      const u16* ly = (const u16*)(smem + cur * BUFB + XB);
      short8 av[4], bv[NACC];
#pragma unroll
      for (int m = 0; m < 4; m++) av[m] = *(const short8*)&lx[(wr + m * 16 + r16) * 32 + kh];
#pragma unroll
      for (int n = 0; n < NACC; n++) bv[n] = *(const short8*)&ly[(wc + n * 16 + r16) * 32 + kh];
#pragma unroll
      for (int m = 0; m < 4; m++)
#pragma unroll
        for (int n = 0; n < NACC; n++)
          acc[m][n] = __builtin_amdgcn_mfma_f32_16x16x32_bf16(av[m], bv[n], acc[m][n], 0, 0, 0);
      if (++cur >= 3) cur = 0;
    }
  } else {
    // --- TRX: 2-buffer __syncthreads loop ---
    xload(0); stageY(0, 0); xwrite(0);
    __syncthreads();
    for (int tt = 0; tt < nt; ++tt) {
      const int cur = tt & 1;
      if (tt + 1 < nt) {
        xload((tt + 1) * 32);
        stageY(cur ^ 1, (tt + 1) * 32);
      }
      short8 av[4], bv[NACC];
      const u16* xt = (const u16*)(smem + cur * BUFB);
#pragma unroll
      for (int m = 0; m < 4; m++) {
        const u16* rp = &xt[(size_t)(wr + m * 16 + r16) * 34 + kh];
        unsigned* d = (unsigned*)&av[m];
        d[0] = *(const unsigned*)(rp);
        d[1] = *(const unsigned*)(rp + 2);
        d[2] = *(const unsigned*)(rp + 4);
        d[3] = *(const unsigned*)(rp + 6);
      }
      const u16* ly = (const u16*)(smem + cur * BUFB + XB);
#pragma unroll
      for (int n = 0; n < NACC; n++) bv[n] = *(const short8*)&ly[(wc + n * 16 + r16) * 32 + kh];
#pragma unroll
      for (int m = 0; m < 4; m++)
#pragma unroll
        for (int n = 0; n < NACC; n++)
          acc[m][n] = __builtin_amdgcn_mfma_f32_16x16x32_bf16(av[m], bv[n], acc[m][n], 0, 0, 0);
      if (tt + 1 < nt) xwrite(cur ^ 1);
      __syncthreads();
    }
  }

  // --- register-stage epilogue math (bias / tanh / mask), masks hoisted ---
  if (flags & (FLAG_BIAS | FLAG_TANH | FLAG_MASK)) {
    float rmv[16];
    if (flags & FLAG_MASK) {
#pragma unroll
      for (int m = 0; m < 4; m++)
#pragma unroll
        for (int j = 0; j < 4; j++)
          rmv[m * 4 + j] =
              (float)rmask[(size_t)bz * rms + rb + wr + m * 16 + ((lane >> 4) << 2) + j];
    }
#pragma unroll
    for (int n = 0; n < NACC; n++) {
      const int c = cb + wc + n * 16 + r16;
      const float bcol = (flags & FLAG_BIAS) ? biasE[c] : 0.f;
      const float cmv = (flags & FLAG_MASK) ? (float)cmask[(size_t)bz * cms + c] : 1.f;
#pragma unroll
      for (int m = 0; m < 4; m++) {
#pragma unroll
        for (int j = 0; j < 4; j++) {
          float v = acc[m][n][j] + bcol;
          if (flags & FLAG_TANH) v = fast_tanh(v);
          if (flags & FLAG_MASK) v *= cmv * rmv[m * 4 + j];
          acc[m][n][j] = v;
        }
      }
    }
  }

  const size_t ocol = (flags & FLAG_SPLITN) ? (size_t)((cb >> 8) * 512 + (cb & 255))
                                            : (size_t)obase + (size_t)lz * ols + cb;
  const int lsc = (flags & FLAG_SPLITN) ? (cb >> 8) : lz;
  const int shalf = (cb >> 7) & 1;
  const float* svec = (flags & FLAG_SCORE)
      ? sbaseE + (size_t)lsc * 512 + svoff + ((flags & FLAG_SPLITN) ? (cb & 255) : cb)
      : nullptr;

  if (flags & FLAG_NSTORE) {
#pragma unroll
    for (int m = 0; m < 4; m++) {
      __syncthreads();
      float* bb = (float*)smem;
#pragma unroll
      for (int n = 0; n < NACC; n++)
#pragma unroll
        for (int j = 0; j < 4; j++)
          bb[(size_t)((wid >> 1) * 16 + ((lane >> 4) << 2) + j) * BW + wc + n * 16 + r16] =
              acc[m][n][j];
      __syncthreads();
      const int lr = t >> 3;
      const int c0 = (t & 7) * (BN / 8);
      const int g = rb + (lr >> 4) * 64 + m * 16 + (lr & 15);
      const float4* src = (const float4*)&bb[(size_t)lr * BW + c0];
      if (flags & FLAG_BF16) {
        u16* op = (u16*)Outv + (size_t)bz * obs + (size_t)g * ldo + ocol + c0;
#pragma unroll
        for (int q = 0; q < BN / 64; q++) {
          const float4 f0 = src[2 * q], f1 = src[2 * q + 1];
          uint4 u;
          u.x = cvtpk(f0.x, f0.y); u.y = cvtpk(f0.z, f0.w);
          u.z = cvtpk(f1.x, f1.y); u.w = cvtpk(f1.z, f1.w);
          ((uint4*)op)[q] = u;
        }
      } else {
        float* op = (float*)Outv + (size_t)bz * obs + (size_t)g * ldo + ocol + c0;
        float sp = 0.f;
#pragma unroll
        for (int q = 0; q < BN / 32; q++) {
          const float4 v = src[q];
          ((float4*)op)[q] = v;
          if (flags & FLAG_SCORE) {
            const float4 wv = *(const float4*)&svec[c0 + q * 4];
            sp += v.x * wv.x + v.y * wv.y + v.z * wv.z + v.w * wv.w;
          }
        }
        if (flags & FLAG_SCORE) {
          sp += __shfl_xor(sp, 1);
          sp += __shfl_xor(sp, 2);
          sp += __shfl_xor(sp, 4);
          if ((t & 7) == 0)
            soutE[(size_t)shalf * shsE + (size_t)lsc * slsE +
                  (size_t)bz * (gy * 128) + (g - gofs)] = sp;
        }
      }
    }
  }

  if constexpr (BN == 128 && !TRX) {
    if (flags & FLAG_TSTORE) {
#pragma unroll
      for (int np = 0; np < 2; np++) {
        __syncthreads();
        float* bb = (float*)smem;
#pragma unroll
        for (int q = 0; q < 2; q++) {
          const int n = np * 2 + q;
#pragma unroll
          for (int m = 0; m < 4; m++)
#pragma unroll
            for (int j = 0; j < 4; j++)
              bb[(size_t)((wid & 1) * 32 + q * 16 + r16) * 132 + wr + m * 16 + ((lane >> 4) << 2) + j] =
                  acc[m][n][j];
        }
        __syncthreads();
        const int lc = t >> 2, r0 = (t & 3) * 32;
        const int colg = cb + (lc >> 5) * 64 + (np * 2 + ((lc >> 4) & 1)) * 16 + (lc & 15);
        const float4* src = (const float4*)&bb[(size_t)lc * 132 + r0];
        u16* op = ToutE + (size_t)lz * tols + (size_t)bz * tobsE +
                  (size_t)colg * tldoE + (rb - gofs) + r0;
#pragma unroll
        for (int q = 0; q < 4; q++) {
          const float4 f0 = src[2 * q], f1 = src[2 * q + 1];
          uint4 u;
          u.x = cvtpk(f0.x, f0.y); u.y = cvtpk(f0.z, f0.w);
          u.z = cvtpk(f1.x, f1.y); u.w = cvtpk(f1.z, f1.w);
          ((uint4*)op)[q] = u;
        }
      }
    }
  }
}

// 5 weight tensors f32 [L][256][256] -> bf16 transposed; z = which*4 + l
__global__ void wtrans5(const float* __restrict__ iU, const float* __restrict__ iP2C,
                        const float* __restrict__ iC2P, const float* __restrict__ iHC,
                        const float* __restrict__ iHP,
                        u16* __restrict__ oU, u16* __restrict__ oP2C,
                        u16* __restrict__ oC2P, u16* __restrict__ oHC,
                        u16* __restrict__ oHP) {
  __shared__ float tl[32][33];
  const int which = blockIdx.z >> 2, l = blockIdx.z & 3;
  const float* in;
  u16* out;
  switch (which) {
    case 0: in = iU;   out = oU;   break;
    case 1: in = iP2C; out = oP2C; break;
    case 2: in = iC2P; out = oC2P; break;
    case 3: in = iHC;  out = oHC;  break;
    default: in = iHP; out = oHP;  break;
  }
  const size_t bo = (size_t)l * 256 * 256;
  const int c0 = blockIdx.x * 32, r0 = blockIdx.y * 32;
  for (int i = threadIdx.y; i < 32; i += 8)
    tl[i][threadIdx.x] = in[bo + (size_t)(r0 + i) * 256 + c0 + threadIdx.x];
  __syncthreads();
  for (int i = threadIdx.y; i < 32; i += 8)
    out[bo + (size_t)(c0 + i) * 256 + r0 + threadIdx.x] = f2bf(tl[threadIdx.x][i]);
}

// both feature tensors f32 -> bf16 in one launch
__global__ void conv_both(const float* __restrict__ a, u16* __restrict__ oa, int n4a,
                          const float* __restrict__ b, u16* __restrict__ ob, int n4b) {
  int i = blockIdx.x * 256 + threadIdx.x;
  const float* in;
  u16* out;
  if (i < n4a) { in = a; out = oa; }
  else { i -= n4a; if (i >= n4b) return; in = b; out = ob; }
  const float4 v = ((const float4*)in)[i];
  ushort4 o;
  o.x = f2bf(v.x); o.y = f2bf(v.y); o.z = f2bf(v.z); o.w = f2bf(v.w);
  ((ushort4*)out)[i] = o;
}

// fused masked-softmax + chunked pooling. grid (16, 20): y<4 comp, y>=4 prot.
// Each block recomputes the per-layer softmax reductions (max, sum) over the
// full token range (cheap), then pools its 128-token chunk for all 4 layers.
__global__ __launch_bounds__(256)
void poolsm(const float* __restrict__ sCt, const float* __restrict__ sCx,
            const float* __restrict__ sPt, const float* __restrict__ sPx,
            long long shsC, long long shsP,
            const int* __restrict__ cmask, const int* __restrict__ pmask,
            const float* __restrict__ cfeat, const float* __restrict__ pfeat,
            float* __restrict__ partC, float* __restrict__ partP) {
  const int b = blockIdx.x, y = blockIdx.y, t = threadIdx.x;
  int ntok, ls, tok0;
  long long shs;
  const float *st, *sx;
  const int* mk;
  const float* feat;
  float* part;
  if (y < 4) {
    ntok = 512; ls = 8192; shs = shsC;
    st = sCt + b * 512; sx = sCx + b * 512;
    mk = cmask + b * 512;
    feat = cfeat + (size_t)b * 512 * 256;
    tok0 = y * 128;
    part = partC + ((size_t)b * 4 + y) * 1024;
  } else {
    ntok = 2048; ls = 32768; shs = shsP;
    st = sPt + b * 2048; sx = sPx + b * 2048;
    mk = pmask + b * 2048;
    feat = pfeat + (size_t)b * 2048 * 256;
    tok0 = (y - 4) * 128;
    part = partP + ((size_t)b * 16 + (y - 4)) * 1024;
  }
  __shared__ float red[256];
  __shared__ float minv[4][2];
  __shared__ float e[4][128];
  for (int l = 0; l < 4; l++) {
    const float* s1 = st + (size_t)l * ls;
    const float* s2 = sx + (size_t)l * ls;
    float m = -1e30f;
    for (int i = t; i < ntok; i += 256)
      m = fmaxf(m, s1[i] + s1[shs + i] + s2[i] + s2[shs + i]);
    red[t] = m;
    __syncthreads();
    for (int h = 128; h; h >>= 1) { if (t < h) red[t] = fmaxf(red[t], red[t + h]); __syncthreads(); }
    const float smax = red[0];
    __syncthreads();
    float sum = 0.f;
    for (int i = t; i < ntok; i += 256)
      sum += __expf(s1[i] + s1[shs + i] + s2[i] + s2[shs + i] - smax) * (float)mk[i];
    red[t] = sum;
    __syncthreads();
    for (int h = 128; h; h >>= 1) { if (t < h) red[t] += red[t + h]; __syncthreads(); }
    if (t == 0) { minv[l][0] = smax; minv[l][1] = 1.f / (red[0] + 1e-6f); }
    __syncthreads();
  }
  // normalized weights for this chunk (all 4 layers)
  for (int i = t; i < 512; i += 256) {
    const int l = i >> 7, j = i & 127, tk = tok0 + j;
    const float* s1 = st + (size_t)l * ls;
    const float* s2 = sx + (size_t)l * ls;
    e[l][j] = __expf(s1[tk] + s1[shs + tk] + s2[tk] + s2[shs + tk] - minv[l][0]) *
              (float)mk[tk] * minv[l][1];
  }
  __syncthreads();
  const int d = t;
  float a0 = 0.f, a1 = 0.f, a2 = 0.f, a3 = 0.f;
  for (int j = 0; j < 128; j++) {
    const float f = feat[(size_t)(tok0 + j) * 256 + d];
    a0 += e[0][j] * f; a1 += e[1][j] * f; a2 += e[2][j] * f; a3 += e[3][j] * f;
  }
  part[d] = a0; part[256 + d] = a1; part[512 + d] = a2; part[768 + d] = a3;
}

// fused: reduce partials -> pool[1024] in LDS -> final GEMM -> out[b][256].
// grid (16, 2): y=0 comp (4 chunks, W_cc), y=1 prot (16 chunks, W_cp). block (256,4).
__global__ __launch_bounds__(1024)
void poolfinal(const float* __restrict__ partC, const float* __restrict__ partP,
               const float* __restrict__ W_cc, const float* __restrict__ b_cc,
               const float* __restrict__ W_cp, const float* __restrict__ b_cp,
               float* __restrict__ out_cf, float* __restrict__ out_pf) {
  const int b = blockIdx.x;
  const int tid = threadIdx.y * 256 + threadIdx.x;
  __shared__ float pool[1024];
  __shared__ float red[4][256];
  const float* part;
  const float* W;
  const float* bias;
  float* outp;
  int nch;
  if (blockIdx.y == 0) { part = partC + (size_t)b * 4 * 1024;  W = W_cc; bias = b_cc; outp = out_cf; nch = 4; }
  else                 { part = partP + (size_t)b * 16 * 1024; W = W_cp; bias = b_cp; outp = out_pf; nch = 16; }
  float s = 0.f;
  for (int ch = 0; ch < nch; ch++) s += part[(size_t)ch * 1024 + tid];
  pool[tid] = s;
  __syncthreads();
  const int n = threadIdx.x, q = threadIdx.y;
  float acc = 0.f;
  const float* w = W + (size_t)q * 256 * 256;
  const float* p = pool + q * 256;
  for (int k = 0; k < 256; k++) acc += p[k] * w[(size_t)k * 256 + n];
  red[q][n] = acc;
  __syncthreads();
  if (q == 0) outp[b * 256 + n] = red[0][n] + red[1][n] + red[2][n] + red[3][n] + bias[n];
}

// ---------------------------------------------------------------------------
static inline void launch_gemm(hipStream_t s, int BN, int TRX,
                               const u16* X, long long xbs, long long xls, int ldx,
                               const u16* Y, long long ybs, long long yls, int ldy,
                               void* Out, long long obs, long long ols, int obase, int ldo,
                               u16* Tout, long long tobs, long long tols, int tldo,
                               int M, int N, int K, int nz, int flags,
                               const float* bias, const int* rm, int rms,
                               const int* cm, int cms,
                               const float* sbase = nullptr, float* sout = nullptr,
                               long long sls = 0, int svoff = 0, long long shs = 0,
                               const u16* X2 = nullptr, long long xbs2 = 0,
                               const u16* Y2 = nullptr, const float* bias2 = nullptr,
                               const float* sbase2 = nullptr, float* sout2 = nullptr,
                               long long sls2 = 0, long long shs2 = 0,
                               u16* Tout2 = nullptr, long long tobs2 = 0, int tldo2 = 0,
                               int msplit = 0) {
  const int gx = N / BN, gy = M / 128;
  const int nb = gx * gy * nz;
  if (BN == 128 && !TRX)
    gemm_nt<128, 0><<<dim3(nb), dim3(256), 0, s>>>(X, xbs, xls, ldx, Y, ybs, yls, ldy,
                                                   Out, obs, ols, obase, ldo,
                                                   Tout, tobs, tols, tldo,
                                                   K, gx, gy, flags, bias, rm, rms, cm, cms,
                                                   sbase, sout, sls, svoff, shs,
                                                   X2, xbs2, Y2, bias2, sbase2, sout2,
                                                   sls2, shs2, Tout2, tobs2, tldo2, msplit);
  else if (!TRX)
    gemm_nt<256, 0><<<dim3(nb), dim3(256), 0, s>>>(X, xbs, xls, ldx, Y, ybs, yls, ldy,
                                                   Out, obs, ols, obase, ldo,
                                                   Tout, tobs, tols, tldo,
                                                   K, gx, gy, flags, bias, rm, rms, cm, cms,
                                                   sbase, sout, sls, svoff, shs,
                                                   X2, xbs2, Y2, bias2, sbase2, sout2,
                                                   sls2, shs2, Tout2, tobs2, tldo2, msplit);
  else
    gemm_nt<256, 1><<<dim3(nb), dim3(256), 0, s>>>(X, xbs, xls, ldx, Y, ybs, yls, ldy,
                                                   Out, obs, ols, obase, ldo,
                                                   Tout, tobs, tols, tldo,
                                                   K, gx, gy, flags, bias, rm, rms, cm, cms,
                                                   sbase, sout, sls, svoff, shs,
                                                   X2, xbs2, Y2, bias2, sbase2, sout2,
                                                   sls2, shs2, Tout2, tobs2, tldo2, msplit);
}

extern "C" void kernel_launch(void* const* d_in, const int* in_sizes, int n_in,
                              void* d_out, int out_size, void* d_ws, size_t ws_size,
                              hipStream_t stream) {
  (void)in_sizes; (void)n_in; (void)out_size; (void)ws_size;
  enum { Bc = 16, LCc = 512, LPc = 2048, Dc = 256, Lc = 4 };

  const float* comp_feat = (const float*)d_in[0];
  const int*   comp_mask = (const int*)d_in[1];
  const float* prot_feat = (const float*)d_in[2];
  const int*   prot_mask = (const int*)d_in[3];
  const float* U     = (const float*)d_in[4];
  const float* W_p2c = (const float*)d_in[5];
  const float* b_p2c = (const float*)d_in[6];
  const float* W_c2p = (const float*)d_in[7];
  const float* b_c2p = (const float*)d_in[8];
  const float* W_hc  = (const float*)d_in[9];
  const float* b_hc  = (const float*)d_in[10];
  const float* W_hp  = (const float*)d_in[11];
  const float* b_hp  = (const float*)d_in[12];
  const float* W_ac  = (const float*)d_in[13];
  const float* b_ac  = (const float*)d_in[14];
  const float* W_ap  = (const float*)d_in[15];
  const float* b_ap  = (const float*)d_in[16];
  const float* W_cc  = (const float*)d_in[17];
  const float* b_cc  = (const float*)d_in[18];
  const float* W_cp  = (const float*)d_in[19];
  const float* b_cp  = (const float*)d_in[20];

  float* out_cf = (float*)d_out;                       // [16][256]
  float* out_pf = out_cf + Bc * Dc;                    // [16][256]
  float* CLW = out_pf + Bc * Dc;                       // [16][512][2048]
  float* PLW = CLW + (size_t)Bc * LCc * 2 * Dc * Lc;   // contiguous after CLW

  char* wsp = (char*)d_ws;
  size_t off = 0;
  auto carve = [&](size_t bytes) -> char* {
    char* p = wsp + off;
    off += (bytes + 255) & ~(size_t)255;
    return p;
  };
  u16* cfb   = (u16*)carve((size_t)Bc * LCc * Dc * 2);  // pfb contiguous after
  u16* pfb   = (u16*)carve((size_t)Bc * LPc * Dc * 2);
  u16* Utb   = (u16*)carve((size_t)Lc * Dc * Dc * 2);
  u16* Wp2ct = (u16*)carve((size_t)Lc * Dc * Dc * 2);
  u16* Wc2pt = (u16*)carve((size_t)Lc * Dc * Dc * 2);
  u16* Whct  = (u16*)carve((size_t)Lc * Dc * Dc * 2);
  u16* Whpt  = (u16*)carve((size_t)Lc * Dc * Dc * 2);
  u16* CU_all   = (u16*)carve((size_t)Bc * LCc * Lc * Dc * 2);   // [b*512+c][1024]
  u16* C2Pt_all = (u16*)carve((size_t)Bc * Lc * Dc * LCc * 2);   // [b][l*256+d][512]
  u16* P2Ct_all = (u16*)carve((size_t)Bc * Lc * Dc * LPc * 2);   // [b][l*256+d][2048]
  u16* A_all  = (u16*)carve((size_t)Lc * Bc * LCc * LPc * 2);    // [l][b][c][p]
  float* sCt = (float*)carve((size_t)2 * Lc * Bc * LCc * 4);     // [half][l][b*512+c]
  float* sCx = (float*)carve((size_t)2 * Lc * Bc * LCc * 4);
  float* sPt = (float*)carve((size_t)2 * Lc * Bc * LPc * 4);
  float* sPx = (float*)carve((size_t)2 * Lc * Bc * LPc * 4);
  float* partC = (float*)carve((size_t)Bc * 4 * 1024 * 4);
  float* partP = (float*)carve((size_t)Bc * 16 * 1024 * 4);

  const long long shsC = (long long)Lc * Bc * LCc;
  const long long shsP = (long long)Lc * Bc * LPc;

  // half-1 of sPx is never written by GEMM-3 (BN=256 covers the full slice);
  // zero it up front, off the critical tail.
  hipMemsetAsync(sPx + shsP, 0, (size_t)shsP * 4, stream);

  // --- init: bf16 features (one launch), transposed bf16 weights ---
  {
    const int n4a = Bc * LCc * Dc / 4, n4b = Bc * LPc * Dc / 4;
    conv_both<<<dim3((n4a + n4b + 255) / 256), dim3(256), 0, stream>>>(
        comp_feat, cfb, n4a, prot_feat, pfb, n4b);
  }
  wtrans5<<<dim3(8, 8, 20), dim3(32, 8), 0, stream>>>(U, W_p2c, W_c2p, W_hc, W_hp,
                                                      Utb, Wp2ct, Wc2pt, Whct, Whpt);

  const int LW = 2 * Dc * Lc;  // 2048

  // --- batched-over-layers weight GEMMs (all BN=128: 3 blocks/CU) ---
  launch_gemm(stream, 128, 0, cfb, 0, 0, Dc, Utb, 0, 0, Dc,
              CU_all, 0, 0, 0, Lc * Dc, nullptr, 0, 0, 0,
              Bc * LCc, Lc * Dc, Dc, 1, FLAG_NSTORE | FLAG_BF16,
              nullptr, nullptr, 0, nullptr, 0);
  // Whc+Whp merged (DUAL-M): rows 0..8191 comp, 8192..40959 prot.
  // X2=pfb (same address as cfb+8192*256 via contiguity), xbs2=0.
  launch_gemm(stream, 128, 0, cfb, 0, 0, Dc, Whct, 0, 0, Dc,
              CLW, 0, 0, 0, LW, nullptr, 0, 0, 0,
              Bc * (LCc + LPc), Lc * Dc, Dc, 1,
              FLAG_NSTORE | FLAG_SPLITN | FLAG_BIAS | FLAG_TANH | FLAG_SCORE,
              b_hc, nullptr, 0, nullptr, 0, W_ac, sCt, (long long)Bc * LCc, 0, shsC,
              pfb, 0, Whpt, b_hp, W_ap, sPt, (long long)Bc * LPc, shsP,
              nullptr, 0, 0, Bc * LCc);
  // C2Pt+P2Ct merged (DUAL-M TSTORE): per-batch M=2560, rows 0..511 comp
  // (cfb -> C2Pt_all, b_c2p), rows 512..2559 prot (pfb -> P2Ct_all, b_p2c).
  launch_gemm(stream, 128, 0, cfb, (long long)LCc * Dc, 0, Dc, Wc2pt, 0, 0, Dc,
              nullptr, 0, 0, 0, 0,
              C2Pt_all, (long long)Lc * Dc * LCc, 0, LCc,
              LCc + LPc, Lc * Dc, Dc, Bc, FLAG_TSTORE | FLAG_BIAS | FLAG_TANH,
              b_c2p, nullptr, 0, nullptr, 0,
              nullptr, nullptr, 0, 0, 0,
              pfb, (long long)LPc * Dc, Wp2ct, b_p2c, nullptr, nullptr, 0, 0,
              P2Ct_all, (long long)Lc * Dc * LPc, LPc, LCc);

  // GEMM-1: A_all[l][b] = tanh(CU_l · pf^T)*mask  (BN=128, R17 win)
  launch_gemm(stream, 128, 0,
              CU_all, (long long)LCc * Lc * Dc, Dc, Lc * Dc,
              pfb, (long long)LPc * Dc, 0, Dc,
              A_all, (long long)LCc * LPc, (long long)Bc * LCc * LPc, 0, LPc,
              nullptr, 0, 0, 0,
              LCc, LPc, Dc, Bc * Lc,
              FLAG_NSTORE | FLAG_BF16 | FLAG_TANH | FLAG_MASK,
              nullptr, comp_mask, LCc, prot_mask, LPc);
  // GEMM-2: CLW cross cols + fused cross score halves (K=2048), BN=128
  launch_gemm(stream, 128, 0,
              A_all, (long long)LCc * LPc, (long long)Bc * LCc * LPc, LPc,
              P2Ct_all, (long long)Lc * Dc * LPc, (long long)Dc * LPc, LPc,
              CLW, (long long)LCc * LW, 512, 256, LW, nullptr, 0, 0, 0,
              LCc, Dc, LPc, Bc * Lc, FLAG_NSTORE | FLAG_SCORE,
              nullptr, nullptr, 0, nullptr, 0, W_ac, sCx, (long long)Bc * LCc, 256, shsC);
  // GEMM-3 (TRX): PLW cross cols + fused cross score halves (K=512), BN=256
  launch_gemm(stream, 256, 1,
              A_all, (long long)LCc * LPc, (long long)Bc * LCc * LPc, LPc,
              C2Pt_all, (long long)Lc * Dc * LCc, (long long)Dc * LCc, LCc,
              PLW, (long long)LPc * LW, 512, 256, LW, nullptr, 0, 0, 0,
              LPc, Dc, LCc, Bc * Lc, FLAG_NSTORE | FLAG_SCORE,
              nullptr, nullptr, 0, nullptr, 0, W_ap, sPx, (long long)Bc * LPc, 256, shsP);

  // --- fused softmax+pooling, then final ---
  poolsm<<<dim3(Bc, 20), dim3(256), 0, stream>>>(sCt, sCx, sPt, sPx, shsC, shsP,
                                                 comp_mask, prot_mask,
                                                 comp_feat, prot_feat, partC, partP);
  poolfinal<<<dim3(Bc, 2), dim3(256, 4), 0, stream>>>(partC, partP, W_cc, b_cc, W_cp, b_cp,
                                                      out_cf, out_pf);
}

// Round 22
// 533.290 us; speedup vs baseline: 1.0495x; 1.0495x over previous
//
#include <hip/hip_runtime.h>

typedef unsigned short u16;
typedef __attribute__((ext_vector_type(8))) short short8;
typedef __attribute__((ext_vector_type(4))) float f32x4;

#define FLAG_BIAS   1
#define FLAG_TANH   2
#define FLAG_MASK   4
#define FLAG_BF16   8
#define FLAG_NSTORE 16
#define FLAG_TSTORE 32
#define FLAG_SPLITN 64
#define FLAG_SCORE  128

__device__ __forceinline__ float fast_tanh(float x) {
  return 1.f - 2.f / (__expf(2.f * x) + 1.f);
}

__device__ __forceinline__ u16 f2bf(float f) {
  unsigned u = __float_as_uint(f);
  return (u16)((u + 0x7fffu + ((u >> 16) & 1u)) >> 16); // RNE
}

__device__ __forceinline__ unsigned cvtpk(float lo, float hi) {
  unsigned r;
  asm("v_cvt_pk_bf16_f32 %0, %1, %2" : "=v"(r) : "v"(lo), "v"(hi));
  return r;
}

__device__ __forceinline__ void gload_lds16(const void* g, void* l) {
  __builtin_amdgcn_global_load_lds(
      (const __attribute__((address_space(1))) unsigned int*)g,
      (__attribute__((address_space(3))) unsigned int*)l, 16, 0, 0);
}

// ---------------------------------------------------------------------------
// Generic GEMM: Out[r][c] = sum_k X[r][k] * Y[c][k]
//   TRX=0: 3-buffer prefetch-2 pipeline, raw s_barrier + counted vmcnt.
//   TRX=1: reg-transpose staged X, 2-buffer __syncthreads loop.
// BM=128, BN=128/256, BK=32, 4 waves, mfma_f32_16x16x32_bf16.
// 1-D grid, XCD-chunked swizzle. f32 4x32 LDS-bounce epilogue, cvt_pk on read.
// LDS sizing: TSTORE bounce (BN=128) needs 64*132*4 = 33792 B (R6/R7 bug).
// FLAG_SCORE (f32 NSTORE): partial dot over this block's BN-col slice ->
//   sout[half*shs + lsc*sls + bz*(gy*128) + row], half=(cb>>7)&1. Disjoint
//   per-block writes; softmax_w sums the halves. Deterministic.
// DUAL-M (msplit>0): rows >= msplit use {Y2, bias2, sbase2, sout2, sls2,
//   shs2} and row index g-msplit. Block-uniform (msplit % 128 == 0).
//   Used to merge the Whc (comp, M=8192) and Whp (prot, M=32768) GEMMs:
//   cfb/pfb and CLW/PLW are contiguous, so one M=40960 launch covers both.
// This is the R20 configuration — measured best (534.7 us). R21's TSTORE
// merge + poolsm fusion regressed (+25 us) and is reverted.
// ---------------------------------------------------------------------------
template <int BN, int TRX>
__global__ __launch_bounds__(256)
void gemm_nt(const u16* __restrict__ X, long long xbs, long long xls, int ldx,
             const u16* __restrict__ Y, long long ybs, long long yls, int ldy,
             void* __restrict__ Outv, long long obs, long long ols, int obase, int ldo,
             u16* __restrict__ Tout, long long tobs, long long tols, int tldo,
             int K, int gx, int gy, int flags,
             const float* __restrict__ bias,
             const int* __restrict__ rmask, int rms,
             const int* __restrict__ cmask, int cms,
             const float* __restrict__ sbase, float* __restrict__ sout,
             long long sls, int svoff, long long shs,
             const u16* __restrict__ Y2, const float* __restrict__ bias2,
             const float* __restrict__ sbase2, float* __restrict__ sout2,
             long long sls2, long long shs2, int msplit) {
  constexpr int NACC = BN / 32;
  constexpr int YB = BN * 32 * 2;             // Y bytes per buffer
  constexpr int XB = TRX ? 8704 : 8192;       // X bytes per buffer (TRX: [128][34])
  constexpr int BUFB = XB + YB;
  constexpr int NBUF = TRX ? 2 : 3;           // pipeline depth
  constexpr int BW = BN + 4;                  // f32 bounce row stride
  constexpr int NSTB = 32 * BW * 4;           // NSTORE bounce bytes
  constexpr int TSTB = (BN == 128 && !TRX) ? 64 * 132 * 4 : 0;  // TSTORE bounce
  constexpr int EPIB = (NSTB > TSTB) ? NSTB : TSTB;
  constexpr int SMEMB = (NBUF * BUFB > EPIB) ? NBUF * BUFB : EPIB;
  __shared__ __align__(16) char smem[SMEMB];
  const int t = threadIdx.x;
  const int lane = t & 63, wid = t >> 6;
  const int wr = (wid >> 1) * 64, wc = (wid & 1) * (BN / 2);
  // XCD-chunked bijective swizzle (gridDim.x % 8 == 0 for all launches)
  const int lin = blockIdx.x;
  const int w = (lin & 7) * ((int)gridDim.x >> 3) + (lin >> 3);
  const int bx = w % gx;
  const int wy = w / gx;
  const int by = wy % gy;
  const int z = wy / gy;
  const int bz = z & 15, lz = z >> 4;
  const int rb = by * 128;
  const int cb = bx * BN;
  // DUAL-M block-uniform selection
  const bool dual = (msplit > 0) && (rb >= msplit);
  const u16* Yeff = dual ? Y2 : Y;
  const float* biasE = dual ? bias2 : bias;
  const float* sbaseE = dual ? sbase2 : sbase;
  float* soutE = dual ? sout2 : sout;
  const long long slsE = dual ? sls2 : sls;
  const long long shsE = dual ? shs2 : shs;
  const int gofs = dual ? msplit : 0;
  // TRX: rb indexes X *columns* (M); rows are K.
  const u16* Xb = X + (size_t)bz * xbs + (size_t)lz * xls +
                  (TRX ? (size_t)rb : (size_t)rb * ldx);
  const u16* Yb = Yeff + (size_t)bz * ybs + (size_t)lz * yls + (size_t)cb * ldy;
  const int srow = t >> 2, scol = (t & 3) * 8;
  const int r16 = lane & 15, kh = (lane >> 4) * 8;

  f32x4 acc[4][NACC];
#pragma unroll
  for (int m = 0; m < 4; m++)
#pragma unroll
    for (int n = 0; n < NACC; n++) acc[m][n] = (f32x4){0.f, 0.f, 0.f, 0.f};

  auto stageY = [&](int buf, int kk) {
    char* dst = smem + buf * BUFB + XB + t * 16;
#pragma unroll
    for (int j = 0; j < YB / 4096; j++)
      gload_lds16(Yb + (size_t)(j * 64 + srow) * ldy + kk + scol, dst + j * 4096);
  };
  auto stageX = [&](int buf, int kk) {
    char* dst = smem + buf * BUFB + t * 16;
#pragma unroll
    for (int j = 0; j < 2; j++)
      gload_lds16(Xb + (size_t)(j * 64 + srow) * ldx + kk + scol, dst + j * 4096);
  };
  auto stage = [&](int buf, int kk) { stageX(buf, kk); stageY(buf, kk); };
  // TRX register staging: load 2 K-rows x 8 M-cols, write transposed pairs
  uint4 xa, xb2;
  const int tc0 = (t >> 4) * 2, tp8 = (t & 15) * 8;
  auto xload = [&](int kk) {
    xa  = *(const uint4*)&Xb[(size_t)(kk + tc0) * ldx + tp8];
    xb2 = *(const uint4*)&Xb[(size_t)(kk + tc0 + 1) * ldx + tp8];
  };
  auto xwrite = [&](int buf) {
    u16* xt = (u16*)(smem + buf * BUFB);
    const unsigned* a = (const unsigned*)&xa;
    const unsigned* b = (const unsigned*)&xb2;
#pragma unroll
    for (int w2 = 0; w2 < 4; w2++) {
      const unsigned lo = (a[w2] & 0xffffu) | (b[w2] << 16);
      const unsigned hi = (a[w2] >> 16) | (b[w2] & 0xffff0000u);
      *(unsigned*)&xt[(size_t)(tp8 + 2 * w2) * 34 + tc0] = lo;
      *(unsigned*)&xt[(size_t)(tp8 + 2 * w2 + 1) * 34 + tc0] = hi;
    }
  };

  const int nt = K >> 5;
  if constexpr (!TRX) {
    // --- 3-buffer prefetch-2 pipeline, counted vmcnt, one s_barrier/iter ---
    stage(0, 0);
    if (nt > 1) stage(1, 32);
    int cur = 0;
    for (int tt = 0; tt < nt; ++tt) {
      if (tt + 1 < nt) {
        if constexpr (BN == 128) asm volatile("s_waitcnt vmcnt(4)" ::: "memory");
        else                     asm volatile("s_waitcnt vmcnt(6)" ::: "memory");
      } else {
        asm volatile("s_waitcnt vmcnt(0)" ::: "memory");
      }
      __builtin_amdgcn_sched_barrier(0);
      __builtin_amdgcn_s_barrier();   // all waves: tile tt resident in buf cur
      if (tt + 2 < nt) {
        int nxt = cur + 2; if (nxt >= 3) nxt -= 3;
        stage(nxt, (tt + 2) * 32);
      }
      const u16* lx = (const u16*)(smem + cur * BUFB);
      const u16* ly = (const u16*)(smem + cur * BUFB + XB);
      short8 av[4], bv[NACC];
#pragma unroll
      for (int m = 0; m < 4; m++) av[m] = *(const short8*)&lx[(wr + m * 16 + r16) * 32 + kh];
#pragma unroll
      for (int n = 0; n < NACC; n++) bv[n] = *(const short8*)&ly[(wc + n * 16 + r16) * 32 + kh];
#pragma unroll
      for (int m = 0; m < 4; m++)
#pragma unroll
        for (int n = 0; n < NACC; n++)
          acc[m][n] = __builtin_amdgcn_mfma_f32_16x16x32_bf16(av[m], bv[n], acc[m][n], 0, 0, 0);
      if (++cur >= 3) cur = 0;
    }
  } else {
    // --- TRX: 2-buffer __syncthreads loop ---
    xload(0); stageY(0, 0); xwrite(0);
    __syncthreads();
    for (int tt = 0; tt < nt; ++tt) {
      const int cur = tt & 1;
      if (tt + 1 < nt) {
        xload((tt + 1) * 32);
        stageY(cur ^ 1, (tt + 1) * 32);
      }
      short8 av[4], bv[NACC];
      const u16* xt = (const u16*)(smem + cur * BUFB);
#pragma unroll
      for (int m = 0; m < 4; m++) {
        const u16* rp = &xt[(size_t)(wr + m * 16 + r16) * 34 + kh];
        unsigned* d = (unsigned*)&av[m];
        d[0] = *(const unsigned*)(rp);
        d[1] = *(const unsigned*)(rp + 2);
        d[2] = *(const unsigned*)(rp + 4);
        d[3] = *(const unsigned*)(rp + 6);
      }
      const u16* ly = (const u16*)(smem + cur * BUFB + XB);
#pragma unroll
      for (int n = 0; n < NACC; n++) bv[n] = *(const short8*)&ly[(wc + n * 16 + r16) * 32 + kh];
#pragma unroll
      for (int m = 0; m < 4; m++)
#pragma unroll
        for (int n = 0; n < NACC; n++)
          acc[m][n] = __builtin_amdgcn_mfma_f32_16x16x32_bf16(av[m], bv[n], acc[m][n], 0, 0, 0);
      if (tt + 1 < nt) xwrite(cur ^ 1);
      __syncthreads();
    }
  }

  // --- register-stage epilogue math (bias / tanh / mask), masks hoisted ---
  if (flags & (FLAG_BIAS | FLAG_TANH | FLAG_MASK)) {
    float rmv[16];
    if (flags & FLAG_MASK) {
#pragma unroll
      for (int m = 0; m < 4; m++)
#pragma unroll
        for (int j = 0; j < 4; j++)
          rmv[m * 4 + j] =
              (float)rmask[(size_t)bz * rms + rb + wr + m * 16 + ((lane >> 4) << 2) + j];
    }
#pragma unroll
    for (int n = 0; n < NACC; n++) {
      const int c = cb + wc + n * 16 + r16;
      const float bcol = (flags & FLAG_BIAS) ? biasE[c] : 0.f;
      const float cmv = (flags & FLAG_MASK) ? (float)cmask[(size_t)bz * cms + c] : 1.f;
#pragma unroll
      for (int m = 0; m < 4; m++) {
#pragma unroll
        for (int j = 0; j < 4; j++) {
          float v = acc[m][n][j] + bcol;
          if (flags & FLAG_TANH) v = fast_tanh(v);
          if (flags & FLAG_MASK) v *= cmv * rmv[m * 4 + j];
          acc[m][n][j] = v;
        }
      }
    }
  }

  const size_t ocol = (flags & FLAG_SPLITN) ? (size_t)((cb >> 8) * 512 + (cb & 255))
                                            : (size_t)obase + (size_t)lz * ols + cb;
  const int lsc = (flags & FLAG_SPLITN) ? (cb >> 8) : lz;
  const int shalf = (cb >> 7) & 1;
  const float* svec = (flags & FLAG_SCORE)
      ? sbaseE + (size_t)lsc * 512 + svoff + ((flags & FLAG_SPLITN) ? (cb & 255) : cb)
      : nullptr;

  if (flags & FLAG_NSTORE) {
#pragma unroll
    for (int m = 0; m < 4; m++) {
      __syncthreads();
      float* bb = (float*)smem;
#pragma unroll
      for (int n = 0; n < NACC; n++)
#pragma unroll
        for (int j = 0; j < 4; j++)
          bb[(size_t)((wid >> 1) * 16 + ((lane >> 4) << 2) + j) * BW + wc + n * 16 + r16] =
              acc[m][n][j];
      __syncthreads();
      const int lr = t >> 3;
      const int c0 = (t & 7) * (BN / 8);
      const int g = rb + (lr >> 4) * 64 + m * 16 + (lr & 15);
      const float4* src = (const float4*)&bb[(size_t)lr * BW + c0];
      if (flags & FLAG_BF16) {
        u16* op = (u16*)Outv + (size_t)bz * obs + (size_t)g * ldo + ocol + c0;
#pragma unroll
        for (int q = 0; q < BN / 64; q++) {
          const float4 f0 = src[2 * q], f1 = src[2 * q + 1];
          uint4 u;
          u.x = cvtpk(f0.x, f0.y); u.y = cvtpk(f0.z, f0.w);
          u.z = cvtpk(f1.x, f1.y); u.w = cvtpk(f1.z, f1.w);
          ((uint4*)op)[q] = u;
        }
      } else {
        float* op = (float*)Outv + (size_t)bz * obs + (size_t)g * ldo + ocol + c0;
        float sp = 0.f;
#pragma unroll
        for (int q = 0; q < BN / 32; q++) {
          const float4 v = src[q];
          ((float4*)op)[q] = v;
          if (flags & FLAG_SCORE) {
            const float4 wv = *(const float4*)&svec[c0 + q * 4];
            sp += v.x * wv.x + v.y * wv.y + v.z * wv.z + v.w * wv.w;
          }
        }
        if (flags & FLAG_SCORE) {
          sp += __shfl_xor(sp, 1);
          sp += __shfl_xor(sp, 2);
          sp += __shfl_xor(sp, 4);
          if ((t & 7) == 0)
            soutE[(size_t)shalf * shsE + (size_t)lsc * slsE +
                  (size_t)bz * (gy * 128) + (g - gofs)] = sp;
        }
      }
    }
  }

  if constexpr (BN == 128 && !TRX) {
    if (flags & FLAG_TSTORE) {
#pragma unroll
      for (int np = 0; np < 2; np++) {
        __syncthreads();
        float* bb = (float*)smem;
#pragma unroll
        for (int q = 0; q < 2; q++) {
          const int n = np * 2 + q;
#pragma unroll
          for (int m = 0; m < 4; m++)
#pragma unroll
            for (int j = 0; j < 4; j++)
              bb[(size_t)((wid & 1) * 32 + q * 16 + r16) * 132 + wr + m * 16 + ((lane >> 4) << 2) + j] =
                  acc[m][n][j];
        }
        __syncthreads();
        const int lc = t >> 2, r0 = (t & 3) * 32;
        const int colg = cb + (lc >> 5) * 64 + (np * 2 + ((lc >> 4) & 1)) * 16 + (lc & 15);
        const float4* src = (const float4*)&bb[(size_t)lc * 132 + r0];
        u16* op = Tout + (size_t)lz * tols + (size_t)bz * tobs + (size_t)colg * tldo + rb + r0;
#pragma unroll
        for (int q = 0; q < 4; q++) {
          const float4 f0 = src[2 * q], f1 = src[2 * q + 1];
          uint4 u;
          u.x = cvtpk(f0.x, f0.y); u.y = cvtpk(f0.z, f0.w);
          u.z = cvtpk(f1.x, f1.y); u.w = cvtpk(f1.z, f1.w);
          ((uint4*)op)[q] = u;
        }
      }
    }
  }
}

// 5 weight tensors f32 [L][256][256] -> bf16 transposed; z = which*4 + l
__global__ void wtrans5(const float* __restrict__ iU, const float* __restrict__ iP2C,
                        const float* __restrict__ iC2P, const float* __restrict__ iHC,
                        const float* __restrict__ iHP,
                        u16* __restrict__ oU, u16* __restrict__ oP2C,
                        u16* __restrict__ oC2P, u16* __restrict__ oHC,
                        u16* __restrict__ oHP) {
  __shared__ float tl[32][33];
  const int which = blockIdx.z >> 2, l = blockIdx.z & 3;
  const float* in;
  u16* out;
  switch (which) {
    case 0: in = iU;   out = oU;   break;
    case 1: in = iP2C; out = oP2C; break;
    case 2: in = iC2P; out = oC2P; break;
    case 3: in = iHC;  out = oHC;  break;
    default: in = iHP; out = oHP;  break;
  }
  const size_t bo = (size_t)l * 256 * 256;
  const int c0 = blockIdx.x * 32, r0 = blockIdx.y * 32;
  for (int i = threadIdx.y; i < 32; i += 8)
    tl[i][threadIdx.x] = in[bo + (size_t)(r0 + i) * 256 + c0 + threadIdx.x];
  __syncthreads();
  for (int i = threadIdx.y; i < 32; i += 8)
    out[bo + (size_t)(c0 + i) * 256 + r0 + threadIdx.x] = f2bf(tl[threadIdx.x][i]);
}

// both feature tensors f32 -> bf16 in one launch
__global__ void conv_both(const float* __restrict__ a, u16* __restrict__ oa, int n4a,
                          const float* __restrict__ b, u16* __restrict__ ob, int n4b) {
  int i = blockIdx.x * 256 + threadIdx.x;
  const float* in;
  u16* out;
  if (i < n4a) { in = a; out = oa; }
  else { i -= n4a; if (i >= n4b) return; in = b; out = ob; }
  const float4 v = ((const float4*)in)[i];
  ushort4 o;
  o.x = f2bf(v.x); o.y = f2bf(v.y); o.z = f2bf(v.z); o.w = f2bf(v.w);
  ((ushort4*)out)[i] = o;
}

// masked softmax over (tanh halves + cross halves) -> normalized weights.
// grid(64, 2): x = l*16+b, y: 0=comp 1=prot.
__global__ __launch_bounds__(256)
void softmax_w(const float* __restrict__ sCt, const float* __restrict__ sCx,
               const float* __restrict__ sPt, const float* __restrict__ sPx,
               long long shsC, long long shsP,
               const int* __restrict__ cmask, const int* __restrict__ pmask,
               float* __restrict__ wC, float* __restrict__ wP) {
  const int l = blockIdx.x >> 4, b = blockIdx.x & 15, t = threadIdx.x;
  const int ntok = blockIdx.y ? 2048 : 512;
  const long long shs = blockIdx.y ? shsP : shsC;
  const float* st = blockIdx.y ? (sPt + l * 32768 + b * 2048) : (sCt + l * 8192 + b * 512);
  const float* sx = blockIdx.y ? (sPx + l * 32768 + b * 2048) : (sCx + l * 8192 + b * 512);
  const int* mk = blockIdx.y ? (pmask + b * 2048) : (cmask + b * 512);
  float* w = blockIdx.y ? (wP + l * 32768 + b * 2048) : (wC + l * 8192 + b * 512);
  __shared__ float red[256];
  __shared__ float e[2048];
  float m = -1e30f;
  for (int i = t; i < ntok; i += 256)
    m = fmaxf(m, st[i] + st[shs + i] + sx[i] + sx[shs + i]);
  red[t] = m;
  __syncthreads();
  for (int h = 128; h; h >>= 1) { if (t < h) red[t] = fmaxf(red[t], red[t + h]); __syncthreads(); }
  const float smax = red[0];
  __syncthreads();
  float sum = 0.f;
  for (int i = t; i < ntok; i += 256) {
    const float ev = __expf(st[i] + st[shs + i] + sx[i] + sx[shs + i] - smax) * (float)mk[i];
    e[i] = ev;
    sum += ev;
  }
  red[t] = sum;
  __syncthreads();
  for (int h = 128; h; h >>= 1) { if (t < h) red[t] += red[t + h]; __syncthreads(); }
  const float inv = 1.f / (red[0] + 1e-6f);
  for (int i = t; i < ntok; i += 256) w[i] = e[i] * inv;
}

// chunked pooling partials over all 4 layers. grid (16, 20)
__global__ __launch_bounds__(256)
void poolpart(const float* __restrict__ wC, const float* __restrict__ wP,
              const float* __restrict__ cfeat, const float* __restrict__ pfeat,
              float* __restrict__ partC, float* __restrict__ partP) {
  const int b = blockIdx.x, y = blockIdx.y, d = threadIdx.x;
  const float* feat;
  const float* wb;
  int ls, tok0;
  float* part;
  if (y < 4) {
    feat = cfeat + (size_t)b * 512 * 256;
    wb = wC + b * 512; ls = 8192; tok0 = y * 128;
    part = partC + ((size_t)b * 4 + y) * 1024;
  } else {
    const int ch = y - 4;
    feat = pfeat + (size_t)b * 2048 * 256;
    wb = wP + b * 2048; ls = 32768; tok0 = ch * 128;
    part = partP + ((size_t)b * 16 + ch) * 1024;
  }
  float a0 = 0.f, a1 = 0.f, a2 = 0.f, a3 = 0.f;
  for (int tok = tok0; tok < tok0 + 128; tok++) {
    const float f = feat[(size_t)tok * 256 + d];
    a0 += wb[tok] * f;
    a1 += wb[ls + tok] * f;
    a2 += wb[2 * ls + tok] * f;
    a3 += wb[3 * ls + tok] * f;
  }
  part[d] = a0; part[256 + d] = a1; part[512 + d] = a2; part[768 + d] = a3;
}

// fused: reduce partials -> pool[1024] in LDS -> final GEMM -> out[b][256].
// grid (16, 2): y=0 comp (4 chunks, W_cc), y=1 prot (16 chunks, W_cp). block (256,4).
__global__ __launch_bounds__(1024)
void poolfinal(const float* __restrict__ partC, const float* __restrict__ partP,
               const float* __restrict__ W_cc, const float* __restrict__ b_cc,
               const float* __restrict__ W_cp, const float* __restrict__ b_cp,
               float* __restrict__ out_cf, float* __restrict__ out_pf) {
  const int b = blockIdx.x;
  const int tid = threadIdx.y * 256 + threadIdx.x;
  __shared__ float pool[1024];
  __shared__ float red[4][256];
  const float* part;
  const float* W;
  const float* bias;
  float* outp;
  int nch;
  if (blockIdx.y == 0) { part = partC + (size_t)b * 4 * 1024;  W = W_cc; bias = b_cc; outp = out_cf; nch = 4; }
  else                 { part = partP + (size_t)b * 16 * 1024; W = W_cp; bias = b_cp; outp = out_pf; nch = 16; }
  float s = 0.f;
  for (int ch = 0; ch < nch; ch++) s += part[(size_t)ch * 1024 + tid];
  pool[tid] = s;
  __syncthreads();
  const int n = threadIdx.x, q = threadIdx.y;
  float acc = 0.f;
  const float* w = W + (size_t)q * 256 * 256;
  const float* p = pool + q * 256;
  for (int k = 0; k < 256; k++) acc += p[k] * w[(size_t)k * 256 + n];
  red[q][n] = acc;
  __syncthreads();
  if (q == 0) outp[b * 256 + n] = red[0][n] + red[1][n] + red[2][n] + red[3][n] + bias[n];
}

// ---------------------------------------------------------------------------
static inline void launch_gemm(hipStream_t s, int BN, int TRX,
                               const u16* X, long long xbs, long long xls, int ldx,
                               const u16* Y, long long ybs, long long yls, int ldy,
                               void* Out, long long obs, long long ols, int obase, int ldo,
                               u16* Tout, long long tobs, long long tols, int tldo,
                               int M, int N, int K, int nz, int flags,
                               const float* bias, const int* rm, int rms,
                               const int* cm, int cms,
                               const float* sbase = nullptr, float* sout = nullptr,
                               long long sls = 0, int svoff = 0, long long shs = 0,
                               const u16* Y2 = nullptr, const float* bias2 = nullptr,
                               const float* sbase2 = nullptr, float* sout2 = nullptr,
                               long long sls2 = 0, long long shs2 = 0, int msplit = 0) {
  const int gx = N / BN, gy = M / 128;
  const int nb = gx * gy * nz;
  if (BN == 128 && !TRX)
    gemm_nt<128, 0><<<dim3(nb), dim3(256), 0, s>>>(X, xbs, xls, ldx, Y, ybs, yls, ldy,
                                                   Out, obs, ols, obase, ldo,
                                                   Tout, tobs, tols, tldo,
                                                   K, gx, gy, flags, bias, rm, rms, cm, cms,
                                                   sbase, sout, sls, svoff, shs,
                                                   Y2, bias2, sbase2, sout2, sls2, shs2, msplit);
  else if (!TRX)
    gemm_nt<256, 0><<<dim3(nb), dim3(256), 0, s>>>(X, xbs, xls, ldx, Y, ybs, yls, ldy,
                                                   Out, obs, ols, obase, ldo,
                                                   Tout, tobs, tols, tldo,
                                                   K, gx, gy, flags, bias, rm, rms, cm, cms,
                                                   sbase, sout, sls, svoff, shs,
                                                   Y2, bias2, sbase2, sout2, sls2, shs2, msplit);
  else
    gemm_nt<256, 1><<<dim3(nb), dim3(256), 0, s>>>(X, xbs, xls, ldx, Y, ybs, yls, ldy,
                                                   Out, obs, ols, obase, ldo,
                                                   Tout, tobs, tols, tldo,
                                                   K, gx, gy, flags, bias, rm, rms, cm, cms,
                                                   sbase, sout, sls, svoff, shs,
                                                   Y2, bias2, sbase2, sout2, sls2, shs2, msplit);
}

extern "C" void kernel_launch(void* const* d_in, const int* in_sizes, int n_in,
                              void* d_out, int out_size, void* d_ws, size_t ws_size,
                              hipStream_t stream) {
  (void)in_sizes; (void)n_in; (void)out_size; (void)ws_size;
  enum { Bc = 16, LCc = 512, LPc = 2048, Dc = 256, Lc = 4 };

  const float* comp_feat = (const float*)d_in[0];
  const int*   comp_mask = (const int*)d_in[1];
  const float* prot_feat = (const float*)d_in[2];
  const int*   prot_mask = (const int*)d_in[3];
  const float* U     = (const float*)d_in[4];
  const float* W_p2c = (const float*)d_in[5];
  const float* b_p2c = (const float*)d_in[6];
  const float* W_c2p = (const float*)d_in[7];
  const float* b_c2p = (const float*)d_in[8];
  const float* W_hc  = (const float*)d_in[9];
  const float* b_hc  = (const float*)d_in[10];
  const float* W_hp  = (const float*)d_in[11];
  const float* b_hp  = (const float*)d_in[12];
  const float* W_ac  = (const float*)d_in[13];
  const float* b_ac  = (const float*)d_in[14];
  const float* W_ap  = (const float*)d_in[15];
  const float* b_ap  = (const float*)d_in[16];
  const float* W_cc  = (const float*)d_in[17];
  const float* b_cc  = (const float*)d_in[18];
  const float* W_cp  = (const float*)d_in[19];
  const float* b_cp  = (const float*)d_in[20];

  float* out_cf = (float*)d_out;                       // [16][256]
  float* out_pf = out_cf + Bc * Dc;                    // [16][256]
  float* CLW = out_pf + Bc * Dc;                       // [16][512][2048]
  float* PLW = CLW + (size_t)Bc * LCc * 2 * Dc * Lc;   // contiguous after CLW

  char* wsp = (char*)d_ws;
  size_t off = 0;
  auto carve = [&](size_t bytes) -> char* {
    char* p = wsp + off;
    off += (bytes + 255) & ~(size_t)255;
    return p;
  };
  u16* cfb   = (u16*)carve((size_t)Bc * LCc * Dc * 2);  // NOTE: pfb contiguous after
  u16* pfb   = (u16*)carve((size_t)Bc * LPc * Dc * 2);
  u16* Utb   = (u16*)carve((size_t)Lc * Dc * Dc * 2);
  u16* Wp2ct = (u16*)carve((size_t)Lc * Dc * Dc * 2);
  u16* Wc2pt = (u16*)carve((size_t)Lc * Dc * Dc * 2);
  u16* Whct  = (u16*)carve((size_t)Lc * Dc * Dc * 2);
  u16* Whpt  = (u16*)carve((size_t)Lc * Dc * Dc * 2);
  u16* CU_all   = (u16*)carve((size_t)Bc * LCc * Lc * Dc * 2);   // [b*512+c][1024]
  u16* C2Pt_all = (u16*)carve((size_t)Bc * Lc * Dc * LCc * 2);   // [b][l*256+d][512]
  u16* P2Ct_all = (u16*)carve((size_t)Bc * Lc * Dc * LPc * 2);   // [b][l*256+d][2048]
  u16* A_all  = (u16*)carve((size_t)Lc * Bc * LCc * LPc * 2);    // [l][b][c][p]
  float* sCt = (float*)carve((size_t)2 * Lc * Bc * LCc * 4);     // [half][l][b*512+c]
  float* sCx = (float*)carve((size_t)2 * Lc * Bc * LCc * 4);
  float* sPt = (float*)carve((size_t)2 * Lc * Bc * LPc * 4);
  float* sPx = (float*)carve((size_t)2 * Lc * Bc * LPc * 4);
  float* wCb = (float*)carve((size_t)Lc * Bc * LCc * 4);
  float* wPb = (float*)carve((size_t)Lc * Bc * LPc * 4);
  float* partC = (float*)carve((size_t)Bc * 4 * 1024 * 4);
  float* partP = (float*)carve((size_t)Bc * 16 * 1024 * 4);

  const long long shsC = (long long)Lc * Bc * LCc;
  const long long shsP = (long long)Lc * Bc * LPc;

  // half-1 of sPx is never written by GEMM-3 (BN=256 covers the full slice);
  // zero it up front, off the critical tail.
  hipMemsetAsync(sPx + shsP, 0, (size_t)shsP * 4, stream);

  // --- init: bf16 features (one launch), transposed bf16 weights ---
  {
    const int n4a = Bc * LCc * Dc / 4, n4b = Bc * LPc * Dc / 4;
    conv_both<<<dim3((n4a + n4b + 255) / 256), dim3(256), 0, stream>>>(
        comp_feat, cfb, n4a, prot_feat, pfb, n4b);
  }
  wtrans5<<<dim3(8, 8, 20), dim3(32, 8), 0, stream>>>(U, W_p2c, W_c2p, W_hc, W_hp,
                                                      Utb, Wp2ct, Wc2pt, Whct, Whpt);

  const int LW = 2 * Dc * Lc;  // 2048

  // --- batched-over-layers weight GEMMs (all BN=128: 3 blocks/CU) ---
  launch_gemm(stream, 128, 0, cfb, 0, 0, Dc, Utb, 0, 0, Dc,
              CU_all, 0, 0, 0, Lc * Dc, nullptr, 0, 0, 0,
              Bc * LCc, Lc * Dc, Dc, 1, FLAG_NSTORE | FLAG_BF16,
              nullptr, nullptr, 0, nullptr, 0);
  // Whc+Whp merged (DUAL-M): rows 0..8191 comp (cfb -> CLW tanh cols, b_hc,
  // W_ac, sCt), rows 8192..40959 prot (pfb -> PLW tanh cols, b_hp, W_ap, sPt).
  launch_gemm(stream, 128, 0, cfb, 0, 0, Dc, Whct, 0, 0, Dc,
              CLW, 0, 0, 0, LW, nullptr, 0, 0, 0,
              Bc * (LCc + LPc), Lc * Dc, Dc, 1,
              FLAG_NSTORE | FLAG_SPLITN | FLAG_BIAS | FLAG_TANH | FLAG_SCORE,
              b_hc, nullptr, 0, nullptr, 0, W_ac, sCt, (long long)Bc * LCc, 0, shsC,
              Whpt, b_hp, W_ap, sPt, (long long)Bc * LPc, shsP, Bc * LCc);
  launch_gemm(stream, 128, 0, cfb, (long long)LCc * Dc, 0, Dc, Wc2pt, 0, 0, Dc,
              nullptr, 0, 0, 0, 0,
              C2Pt_all, (long long)Lc * Dc * LCc, 0, LCc,
              LCc, Lc * Dc, Dc, Bc, FLAG_TSTORE | FLAG_BIAS | FLAG_TANH,
              b_c2p, nullptr, 0, nullptr, 0);
  launch_gemm(stream, 128, 0, pfb, (long long)LPc * Dc, 0, Dc, Wp2ct, 0, 0, Dc,
              nullptr, 0, 0, 0, 0,
              P2Ct_all, (long long)Lc * Dc * LPc, 0, LPc,
              LPc, Lc * Dc, Dc, Bc, FLAG_TSTORE | FLAG_BIAS | FLAG_TANH,
              b_p2c, nullptr, 0, nullptr, 0);

  // GEMM-1: A_all[l][b] = tanh(CU_l · pf^T)*mask  (BN=128, R17 win)
  launch_gemm(stream, 128, 0,
              CU_all, (long long)LCc * Lc * Dc, Dc, Lc * Dc,
              pfb, (long long)LPc * Dc, 0, Dc,
              A_all, (long long)LCc * LPc, (long long)Bc * LCc * LPc, 0, LPc,
              nullptr, 0, 0, 0,
              LCc, LPc, Dc, Bc * Lc,
              FLAG_NSTORE | FLAG_BF16 | FLAG_TANH | FLAG_MASK,
              nullptr, comp_mask, LCc, prot_mask, LPc);
  // GEMM-2: CLW cross cols + fused cross score halves (K=2048), BN=128
  launch_gemm(stream, 128, 0,
              A_all, (long long)LCc * LPc, (long long)Bc * LCc * LPc, LPc,
              P2Ct_all, (long long)Lc * Dc * LPc, (long long)Dc * LPc, LPc,
              CLW, (long long)LCc * LW, 512, 256, LW, nullptr, 0, 0, 0,
              LCc, Dc, LPc, Bc * Lc, FLAG_NSTORE | FLAG_SCORE,
              nullptr, nullptr, 0, nullptr, 0, W_ac, sCx, (long long)Bc * LCc, 256, shsC);
  // GEMM-3 (TRX): PLW cross cols + fused cross score halves (K=512), BN=256
  launch_gemm(stream, 256, 1,
              A_all, (long long)LCc * LPc, (long long)Bc * LCc * LPc, LPc,
              C2Pt_all, (long long)Lc * Dc * LCc, (long long)Dc * LCc, LCc,
              PLW, (long long)LPc * LW, 512, 256, LW, nullptr, 0, 0, 0,
              LPc, Dc, LCc, Bc * Lc, FLAG_NSTORE | FLAG_SCORE,
              nullptr, nullptr, 0, nullptr, 0, W_ap, sPx, (long long)Bc * LPc, 256, shsP);

  // --- fused pooling ---
  softmax_w<<<dim3(Lc * Bc, 2), dim3(256), 0, stream>>>(sCt, sCx, sPt, sPx, shsC, shsP,
                                                        comp_mask, prot_mask, wCb, wPb);
  poolpart<<<dim3(Bc, 20), dim3(256), 0, stream>>>(wCb, wPb, comp_feat, prot_feat, partC, partP);
  poolfinal<<<dim3(Bc, 2), dim3(256, 4), 0, stream>>>(partC, partP, W_cc, b_cc, W_cp, b_cp,
                                                      out_cf, out_pf);
}